// Round 9
// baseline (132.505 us; speedup 1.0000x reference)
//
#include <hip/hip_runtime.h>
#include <math.h>

#define NPTS 262144
#define BATCH 32
#define BPB 64
#define NBLK (BATCH * BPB)        // 2048 blocks
#define NTAIL 40
#define THRESH (NBLK - NTAIL)     // 2008
#define S2N (16 + 24 * BATCH)     // 784

// ---------- wave (64-lane) reductions ----------
__device__ __forceinline__ float wred_sum(float v) {
#pragma unroll
    for (int o = 32; o; o >>= 1) v += __shfl_down(v, o);
    return v;
}
__device__ __forceinline__ unsigned wred_usum(unsigned v) {
#pragma unroll
    for (int o = 32; o; o >>= 1) v += __shfl_down(v, o);
    return v;
}

// ---------- agent-scope (device-coherent, no wbl2) accessors ----------
__device__ __forceinline__ void ast(float* p, float v) {
    __hip_atomic_store(p, v, __ATOMIC_RELAXED, __HIP_MEMORY_SCOPE_AGENT);
}
__device__ __forceinline__ void astu(unsigned* p, unsigned v) {
    __hip_atomic_store(p, v, __ATOMIC_RELAXED, __HIP_MEMORY_SCOPE_AGENT);
}
__device__ __forceinline__ float ald(float* p) {
    return __hip_atomic_load(p, __ATOMIC_RELAXED, __HIP_MEMORY_SCOPE_AGENT);
}
__device__ __forceinline__ unsigned aldu(unsigned* p) {
    return __hip_atomic_load(p, __ATOMIC_RELAXED, __HIP_MEMORY_SCOPE_AGENT);
}

// Partial layout: float pf[27][NBLK], uint pi[9][NBLK] (written agent-scope).
// Rows: 0..4 S, 5..9 T, 10 lse; 11..14 gtz, 15..18 prz, 19..26 minmax pairs.
// pi: 0..4 bincount (rows 1..4 double as gt counts), 5..8 pred counts.
// s2[S2N]: 0..10 global S/T/lse, 11..15 dist, 16+b*24+f per-batch stats.
// counters[0]: arrival count (grid sync); counters[1]: tail-done count.

__global__ __launch_bounds__(256) void bsl_fused(
    const float* __restrict__ outputs, const int* __restrict__ labels,
    const float* __restrict__ points, float* pf, unsigned* pi,
    float* s2, unsigned* counters, float* out, int iters)
{
    const int blk = blockIdx.x;
    const int b = blk / BPB;
    const int seg = blk % BPB;
    const int seg_start = seg * (iters * 1024);
    const int tid = threadIdx.x;

    float S[5] = {0, 0, 0, 0, 0};
    float T[5] = {0, 0, 0, 0, 0};
    float lseacc = 0.f;
    float gtz[4] = {0, 0, 0, 0};
    float prz[4] = {0, 0, 0, 0};
    const float INF = __int_as_float(0x7f800000);
    float mn2x = INF, mx2x = -INF, mn2y = INF, mx2y = -INF;
    float mn3x = INF, mx3x = -INF, mn3y = INF, mx3y = -INF;
    unsigned bc[5] = {0, 0, 0, 0, 0}, prc[4] = {0, 0, 0, 0};

    const float* obase = outputs + (size_t)b * 5 * NPTS;
    const int*   lbase = labels + (size_t)b * NPTS;
    const float* pbase = points + (size_t)b * NPTS * 3;

    for (int it = 0; it < iters; ++it) {
        const int n = seg_start + it * 1024 + tid * 4;
        float4 L[5];
#pragma unroll
        for (int c = 0; c < 5; ++c)
            L[c] = *(const float4*)(obase + (size_t)c * NPTS + n);
        const int4 lab = *(const int4*)(lbase + n);
        const float4* pp = (const float4*)(pbase + (size_t)n * 3);
        const float4 p0 = pp[0], p1 = pp[1], p2 = pp[2];
        const float xs[4] = {p0.x, p0.w, p1.z, p2.y};
        const float ys[4] = {p0.y, p1.x, p1.w, p2.z};
        const float zs[4] = {p0.z, p1.y, p2.x, p2.w};
        const int   lb[4] = {lab.x, lab.y, lab.z, lab.w};
#pragma unroll
        for (int j = 0; j < 4; ++j) {
            float v[5];
#pragma unroll
            for (int c = 0; c < 5; ++c) v[c] = ((const float*)&L[c])[j];
            // first-max argmax (JAX tie-break semantics)
            float best = v[0]; int pred = 0;
#pragma unroll
            for (int c = 1; c < 5; ++c)
                if (v[c] > best) { best = v[c]; pred = c; }
            float e = 0.f;
#pragma unroll
            for (int c = 0; c < 5; ++c) e += __expf(v[c] - best);
            const float lse = best + __logf(e);
            lseacc += lse;
            const int y = lb[j];
#pragma unroll
            for (int c = 0; c < 5; ++c) {
                S[c] += v[c];
                const bool is = (y == c);
                T[c] += is ? (lse - v[c]) : 0.f;
                bc[c] += is ? 1u : 0u;
            }
            const float z = zs[j];
#pragma unroll
            for (int k = 0; k < 4; ++k) {
                const bool gy = (y == k + 1), py = (pred == k + 1);
                gtz[k] += gy ? z : 0.f;
                prz[k] += py ? z : 0.f;
                prc[k] += py ? 1u : 0u;
            }
            const float x = xs[j], yv = ys[j];
            // reference: mp = points*mask -> zeros included in min/max
            const float a2x = (pred == 2) ? x : 0.f;
            const float a2y = (pred == 2) ? yv : 0.f;
            const float a3x = (pred == 3) ? x : 0.f;
            const float a3y = (pred == 3) ? yv : 0.f;
            mn2x = fminf(mn2x, a2x); mx2x = fmaxf(mx2x, a2x);
            mn2y = fminf(mn2y, a2y); mx2y = fmaxf(mx2y, a2y);
            mn3x = fminf(mn3x, a3x); mx3x = fmaxf(mx3x, a3x);
            mn3y = fminf(mn3y, a3y); mx3y = fmaxf(mx3y, a3y);
        }
    }

    float fv[27] = {S[0], S[1], S[2], S[3], S[4],
                    T[0], T[1], T[2], T[3], T[4],
                    lseacc,
                    gtz[0], gtz[1], gtz[2], gtz[3],
                    prz[0], prz[1], prz[2], prz[3],
                    mn2x, mx2x, mn2y, mx2y, mn3x, mx3x, mn3y, mx3y};
    unsigned iv[9] = {bc[0], bc[1], bc[2], bc[3], bc[4],
                      prc[0], prc[1], prc[2], prc[3]};

    __shared__ float sf[4][27];
    __shared__ unsigned si[4][9];
    const int wid = tid >> 6, lane = tid & 63;
#pragma unroll
    for (int vdx = 0; vdx < 27; ++vdx) {
        float r;
        if (vdx < 19) r = wred_sum(fv[vdx]);
        else if (((vdx - 19) & 1) == 0) {
#pragma unroll
            for (int o = 32; o; o >>= 1) fv[vdx] = fminf(fv[vdx], __shfl_down(fv[vdx], o));
            r = fv[vdx];
        } else {
#pragma unroll
            for (int o = 32; o; o >>= 1) fv[vdx] = fmaxf(fv[vdx], __shfl_down(fv[vdx], o));
            r = fv[vdx];
        }
        if (lane == 0) sf[wid][vdx] = r;
    }
#pragma unroll
    for (int vdx = 0; vdx < 9; ++vdx) {
        unsigned r = wred_usum(iv[vdx]);
        if (lane == 0) si[wid][vdx] = r;
    }
    __syncthreads();
    if (tid == 0) {
#pragma unroll
        for (int vdx = 0; vdx < 27; ++vdx) {
            float r;
            if (vdx < 19) r = sf[0][vdx] + sf[1][vdx] + sf[2][vdx] + sf[3][vdx];
            else if (((vdx - 19) & 1) == 0)
                r = fminf(fminf(sf[0][vdx], sf[1][vdx]), fminf(sf[2][vdx], sf[3][vdx]));
            else
                r = fmaxf(fmaxf(sf[0][vdx], sf[1][vdx]), fmaxf(sf[2][vdx], sf[3][vdx]));
            ast(&pf[(size_t)vdx * NBLK + blk], r);       // write-through to L3
        }
#pragma unroll
        for (int vdx = 0; vdx < 9; ++vdx)
            astu(&pi[(size_t)vdx * NBLK + blk],
                 si[0][vdx] + si[1][vdx] + si[2][vdx] + si[3][vdx]);
    }

    // ---- grid sync via arrival counter; last NTAIL arrivals claim tail tasks ----
    __shared__ int s_task;
    if (tid == 0) {
        const unsigned old = __hip_atomic_fetch_add(
            &counters[0], 1u, __ATOMIC_RELEASE, __HIP_MEMORY_SCOPE_AGENT);
        const int t = (int)old - THRESH;
        if (t >= 0) {   // tail block: wait until ALL blocks have released partials
            while (__hip_atomic_load(&counters[0], __ATOMIC_ACQUIRE,
                                     __HIP_MEMORY_SCOPE_AGENT) < (unsigned)NBLK)
                __builtin_amdgcn_s_sleep(2);
        }
        s_task = t;
    }
    __syncthreads();
    const int t = s_task;
    if (t < 0) return;

    // ---- tail task t (0..39); all reads agent-scope (L3-coherent) ----
    __shared__ float red[4];
    if (t < 16) {
        // global row sum: 2048 values, 8 dword loads/thread
        float s = 0.f;
        if (t < 11) {
            float* row = pf + (size_t)t * NBLK;
#pragma unroll
            for (int k = 0; k < 8; ++k) s += ald(row + tid + k * 256);
        } else {
            unsigned* row = pi + (size_t)(t - 11) * NBLK;
#pragma unroll
            for (int k = 0; k < 8; ++k) s += (float)aldu(row + tid + k * 256);
        }
        s = wred_sum(s);
        if (lane == 0) red[wid] = s;
        __syncthreads();
        if (tid == 0) ast(&s2[t], red[0] + red[1] + red[2] + red[3]);
    } else {
        // per-batch row: 32 batches x 64 values; 8 threads per batch
        const int f = t - 16;               // 0..23
        const int bb = tid >> 3, k = tid & 7;
        const int base = bb * BPB;
        float r;
        if (f < 8) {                        // gtz/prz sums (pf rows 11..18)
            float* row = pf + (size_t)(11 + f) * NBLK + base;
            r = 0.f;
#pragma unroll
            for (int j = 0; j < 8; ++j) r += ald(row + k * 8 + j);
#pragma unroll
            for (int o = 4; o; o >>= 1) r += __shfl_xor(r, o);
        } else if (f < 16) {                // minmax (pf rows 19..26)
            const int g = f - 8;
            float* row = pf + (size_t)(19 + g) * NBLK + base;
            r = ald(row + k * 8);
            if ((g & 1) == 0) {
#pragma unroll
                for (int j = 1; j < 8; ++j) r = fminf(r, ald(row + k * 8 + j));
#pragma unroll
                for (int o = 4; o; o >>= 1) r = fminf(r, __shfl_xor(r, o));
            } else {
#pragma unroll
                for (int j = 1; j < 8; ++j) r = fmaxf(r, ald(row + k * 8 + j));
#pragma unroll
                for (int o = 4; o; o >>= 1) r = fmaxf(r, __shfl_xor(r, o));
            }
        } else {                            // gtc (pi rows 1..4), prc (pi rows 5..8)
            const int g = f - 16;
            const int rowi = (g < 4) ? (1 + g) : (5 + (g - 4));
            unsigned* row = pi + (size_t)rowi * NBLK + base;
            r = 0.f;
#pragma unroll
            for (int j = 0; j < 8; ++j) r += (float)aldu(row + k * 8 + j);
#pragma unroll
            for (int o = 4; o; o >>= 1) r += __shfl_xor(r, o);
        }
        if (k == 0) ast(&s2[16 + bb * 24 + f], r);
    }

    // ---- last tail block finalizes ----
    __shared__ int s_last;
    if (tid == 0) {
        const unsigned old2 = __hip_atomic_fetch_add(
            &counters[1], 1u, __ATOMIC_ACQ_REL, __HIP_MEMORY_SCOPE_AGENT);
        s_last = (old2 == NTAIL - 1) ? 1 : 0;
    }
    __syncthreads();
    if (!s_last) return;

    __shared__ float sm[S2N];
    for (int i = tid; i < S2N; i += 256) sm[i] = ald(&s2[i]);
    __syncthreads();
    if (wid != 0) return;                   // finalize on wave 0

    const float BASE_W[5] = {0.8f, 2.0f, 1.5f, 1.5f, 3.5f};
    const int pc[12]  = {1, 1, 1, 2, 2, 2, 3, 3, 3, 4, 4, 4};
    const int prf[12] = {2, 3, 4, 1, 3, 4, 1, 2, 4, 1, 2, 3};
    const float ps[12] = {-1.f, -1.f, -1.f, 1.f, -1.f, -1.f, 1.f, 1.f, -1.f, 1.f, 1.f, 1.f};

    // lane b (< BATCH) computes batch b's clipped weights; others contribute 0
    float w[5] = {0, 0, 0, 0, 0};
    if (lane < BATCH) {
        const float* R = sm + 16 + lane * 24;
        for (int c = 0; c < 5; ++c) w[c] = BASE_W[c];
        float gtm[4], prm[4];
        bool gv[4], pv[4];
#pragma unroll
        for (int k = 0; k < 4; ++k) {
            const float c1 = R[16 + k];
            gv[k] = (c1 > 0.f);
            gtm[k] = R[k] / fmaxf(c1, 1.f);
            const float c2 = R[20 + k];
            pv[k] = (c2 > 0.f);
            prm[k] = R[4 + k] / fmaxf(c2, 1.f);
        }
#pragma unroll
        for (int p = 0; p < 12; ++p) {
            const int cid = pc[p], ref = prf[p];
            float add = 0.f;
            if (pv[cid - 1] && gv[ref - 1]) {
                const float diff = ps[p] * (prm[cid - 1] - gtm[ref - 1]);
                add = 50.f / (1.f + expf(10.f * diff));  // ALPHA*sigmoid(-10*diff)
            }
            w[cid] += add;
            w[ref] += 0.3f * add;
        }
        const float mn2x_ = R[8],  mx2x_ = R[9],  mn2y_ = R[10], mx2y_ = R[11];
        const float mn3x_ = R[12], mx3x_ = R[13], mn3y_ = R[14], mx3y_ = R[15];
        {   // cid=2 vs rb=bounds[3]
            const float dx = mx3x_ - mn3x_ + 1e-7f, dy = mx3y_ - mn3y_ + 1e-7f;
            const float xc0 = (mn2x_ - mn3x_) / dx, xc1 = (mx2x_ - mn3x_) / dx;
            const float yc0 = (mn2y_ - mn3y_) / dy, yc1 = (mx2y_ - mn3y_) / dy;
            const float v0 = (xc0 < 0.1f || xc0 > 0.9f || yc0 < 0.1f || yc0 > 0.9f) ? 1.f : 0.f;
            const float v1 = (xc1 < 0.1f || xc1 > 0.9f || yc1 < 0.1f || yc1 > 0.9f) ? 1.f : 0.f;
            w[2] += 50.f * 0.5f * (v0 + v1);
        }
        {   // cid=3 vs rb=bounds[2]
            const float dx = mx2x_ - mn2x_ + 1e-7f, dy = mx2y_ - mn2y_ + 1e-7f;
            const float xc0 = (mn3x_ - mn2x_) / dx, xc1 = (mx3x_ - mn2x_) / dx;
            const float yc0 = (mn3y_ - mn2y_) / dy, yc1 = (mx3y_ - mn2y_) / dy;
            const float v0 = (xc0 < 0.1f || xc0 > 0.9f || yc0 < 0.1f || yc0 > 0.9f) ? 1.f : 0.f;
            const float v1 = (xc1 < 0.1f || xc1 > 0.9f || yc1 < 0.1f || yc1 > 0.9f) ? 1.f : 0.f;
            w[3] += 50.f * 0.5f * (v0 + v1);
        }
#pragma unroll
        for (int c = 0; c < 5; ++c)
            w[c] = fminf(fmaxf(w[c], 0.1f), 10.f);
    }
    float wsumc[5];
#pragma unroll
    for (int c = 0; c < 5; ++c) wsumc[c] = wred_sum(w[c]);

    if (lane == 0) {
        float dist[5], cw[5], s = 0.f;
#pragma unroll
        for (int c = 0; c < 5; ++c) {
            dist[c] = sm[11 + c];
            cw[c] = 1.f / (sqrtf(dist[c]) + 1e-7f);
            s += cw[c];
        }
        float wf[5], wsum = 0.f, W = 0.f, nllnum = 0.f, Ssum = 0.f;
#pragma unroll
        for (int c = 0; c < 5; ++c) {
            cw[c] = cw[c] / s * 5.f;
            wf[c] = (wsumc[c] / 32.f) * cw[c];
            wsum += wf[c] * dist[c];
            W += wf[c];
            nllnum += wf[c] * sm[5 + c];
            Ssum += wf[c] * sm[c];
        }
        const float nll = nllnum / wsum;
        const float smooth = (W * sm[10] - Ssum) / wsum;
        out[0] = 0.8f * nll + 0.04f * smooth;
    }
}

extern "C" void kernel_launch(void* const* d_in, const int* in_sizes, int n_in,
                              void* d_out, int out_size, void* d_ws, size_t ws_size,
                              hipStream_t stream) {
    const float* outputs = (const float*)d_in[0];
    const int*   labels  = (const int*)d_in[1];
    const float* points  = (const float*)d_in[2];
    float* out = (float*)d_out;

    unsigned* counters = (unsigned*)d_ws;                 // 2 u32 (16B slot)
    float* s2 = (float*)((char*)d_ws + 16);               // 784 floats
    float* pf = s2 + S2N;                                 // 27*2048 floats
    unsigned* pi = (unsigned*)(pf + (size_t)27 * NBLK);   // 9*2048 u32

    const int iters = NPTS / (BPB * 1024);                // 4

    hipMemsetAsync(counters, 0, 8, stream);               // graph-legal reset
    bsl_fused<<<NBLK, 256, 0, stream>>>(outputs, labels, points,
                                        pf, pi, s2, counters, out, iters);
}

// Round 10
// 71.893 us; speedup vs baseline: 1.8431x; 1.8431x over previous
//
#include <hip/hip_runtime.h>
#include <math.h>

#define NPTS 262144
#define BATCH 32
#define BPB 64
#define NBLK (BATCH * BPB)   // 2048
#define NREP 8               // replicas for global accumulators (contention)

// ws layout (bytes):
//   0    : float gsum[NREP][11]   (S[5], T[5], lse)          zero-init
//   352  : uint  gcnt[NREP][5]    (bincount)                 zero-init
//   512  : float bsum[32][8]      (gtz[4], prz[4])           zero-init
//   1536 : uint  bcnt[32][8]      (gtc[4], prc[4])           zero-init
//   2560 : uint  bmx [32][4]      (mapped mx2x,mx2y,mx3x,mx3y) zero-init
//   3072 : uint  bmn [32][4]      (mapped mn2x,mn2y,mn3x,mn3y) 0xFF-init
//   3584 : end

// ---------- wave (64-lane) reductions ----------
__device__ __forceinline__ float wred_sum(float v) {
#pragma unroll
    for (int o = 32; o; o >>= 1) v += __shfl_down(v, o);
    return v;
}
__device__ __forceinline__ unsigned wred_usum(unsigned v) {
#pragma unroll
    for (int o = 32; o; o >>= 1) v += __shfl_down(v, o);
    return v;
}

// order-preserving float<->uint map (monotonic: f1<f2 <=> map(f1)<map(f2))
__device__ __forceinline__ unsigned mapf(float f) {
    unsigned u = __float_as_uint(f);
    return (u & 0x80000000u) ? ~u : (u | 0x80000000u);
}
__device__ __forceinline__ float unmapf(unsigned m) {
    return (m & 0x80000000u) ? __uint_as_float(m ^ 0x80000000u)
                             : __uint_as_float(~m);
}

__global__ __launch_bounds__(256) void bsl_main(
    const float* __restrict__ outputs, const int* __restrict__ labels,
    const float* __restrict__ points,
    float* gsum, unsigned* gcnt, float* bsum, unsigned* bcnt,
    unsigned* bmn, unsigned* bmx, int iters)
{
    const int blk = blockIdx.x;
    const int b = blk / BPB;
    const int seg = blk % BPB;
    const int seg_start = seg * (iters * 1024);
    const int tid = threadIdx.x;

    float S[5] = {0, 0, 0, 0, 0};
    float T[5] = {0, 0, 0, 0, 0};
    float lseacc = 0.f;
    float gtz[4] = {0, 0, 0, 0};
    float prz[4] = {0, 0, 0, 0};
    const float INF = __int_as_float(0x7f800000);
    float mn2x = INF, mx2x = -INF, mn2y = INF, mx2y = -INF;
    float mn3x = INF, mx3x = -INF, mn3y = INF, mx3y = -INF;
    unsigned bc[5] = {0, 0, 0, 0, 0}, prc[4] = {0, 0, 0, 0};

    const float* obase = outputs + (size_t)b * 5 * NPTS;
    const int*   lbase = labels + (size_t)b * NPTS;
    const float* pbase = points + (size_t)b * NPTS * 3;

    for (int it = 0; it < iters; ++it) {
        const int n = seg_start + it * 1024 + tid * 4;
        float4 L[5];
#pragma unroll
        for (int c = 0; c < 5; ++c)
            L[c] = *(const float4*)(obase + (size_t)c * NPTS + n);
        const int4 lab = *(const int4*)(lbase + n);
        const float4* pp = (const float4*)(pbase + (size_t)n * 3);
        const float4 p0 = pp[0], p1 = pp[1], p2 = pp[2];
        const float xs[4] = {p0.x, p0.w, p1.z, p2.y};
        const float ys[4] = {p0.y, p1.x, p1.w, p2.z};
        const float zs[4] = {p0.z, p1.y, p2.x, p2.w};
        const int   lb[4] = {lab.x, lab.y, lab.z, lab.w};
#pragma unroll
        for (int j = 0; j < 4; ++j) {
            float v[5];
#pragma unroll
            for (int c = 0; c < 5; ++c) v[c] = ((const float*)&L[c])[j];
            // first-max argmax (JAX tie-break semantics)
            float best = v[0]; int pred = 0;
#pragma unroll
            for (int c = 1; c < 5; ++c)
                if (v[c] > best) { best = v[c]; pred = c; }
            float e = 0.f;
#pragma unroll
            for (int c = 0; c < 5; ++c) e += __expf(v[c] - best);
            const float lse = best + __logf(e);
            lseacc += lse;
            const int y = lb[j];
#pragma unroll
            for (int c = 0; c < 5; ++c) {
                S[c] += v[c];
                const bool is = (y == c);
                T[c] += is ? (lse - v[c]) : 0.f;
                bc[c] += is ? 1u : 0u;
            }
            const float z = zs[j];
#pragma unroll
            for (int k = 0; k < 4; ++k) {
                const bool gy = (y == k + 1), py = (pred == k + 1);
                gtz[k] += gy ? z : 0.f;
                prz[k] += py ? z : 0.f;
                prc[k] += py ? 1u : 0u;
            }
            const float x = xs[j], yv = ys[j];
            // reference: mp = points*mask -> zeros included in min/max
            const float a2x = (pred == 2) ? x : 0.f;
            const float a2y = (pred == 2) ? yv : 0.f;
            const float a3x = (pred == 3) ? x : 0.f;
            const float a3y = (pred == 3) ? yv : 0.f;
            mn2x = fminf(mn2x, a2x); mx2x = fmaxf(mx2x, a2x);
            mn2y = fminf(mn2y, a2y); mx2y = fmaxf(mx2y, a2y);
            mn3x = fminf(mn3x, a3x); mx3x = fmaxf(mx3x, a3x);
            mn3y = fminf(mn3y, a3y); mx3y = fmaxf(mx3y, a3y);
        }
    }

    float fv[27] = {S[0], S[1], S[2], S[3], S[4],
                    T[0], T[1], T[2], T[3], T[4],
                    lseacc,
                    gtz[0], gtz[1], gtz[2], gtz[3],
                    prz[0], prz[1], prz[2], prz[3],
                    mn2x, mx2x, mn2y, mx2y, mn3x, mx3x, mn3y, mx3y};
    unsigned iv[9] = {bc[0], bc[1], bc[2], bc[3], bc[4],
                      prc[0], prc[1], prc[2], prc[3]};

    __shared__ float sf[4][27];
    __shared__ unsigned si[4][9];
    const int wid = tid >> 6, lane = tid & 63;
#pragma unroll
    for (int vdx = 0; vdx < 27; ++vdx) {
        float r;
        if (vdx < 19) r = wred_sum(fv[vdx]);
        else if (((vdx - 19) & 1) == 0) {
#pragma unroll
            for (int o = 32; o; o >>= 1) fv[vdx] = fminf(fv[vdx], __shfl_down(fv[vdx], o));
            r = fv[vdx];
        } else {
#pragma unroll
            for (int o = 32; o; o >>= 1) fv[vdx] = fmaxf(fv[vdx], __shfl_down(fv[vdx], o));
            r = fv[vdx];
        }
        if (lane == 0) sf[wid][vdx] = r;
    }
#pragma unroll
    for (int vdx = 0; vdx < 9; ++vdx) {
        unsigned r = wred_usum(iv[vdx]);
        if (lane == 0) si[wid][vdx] = r;
    }
    __syncthreads();

    // parallel cross-wave combine + ONE relaxed atomic per value.
    // Plain atomicAdd/Min/Max = device-scope at the coherence point, NO
    // wbl2/inv cache maintenance (the R4/R9 failure mechanism).
    const int rep = blk & (NREP - 1);
    if (tid < 27) {
        float r = sf[0][tid];
        if (tid < 19) {
            r += sf[1][tid] + sf[2][tid] + sf[3][tid];
        } else if (((tid - 19) & 1) == 0) {
            r = fminf(fminf(r, sf[1][tid]), fminf(sf[2][tid], sf[3][tid]));
        } else {
            r = fmaxf(fmaxf(r, sf[1][tid]), fmaxf(sf[2][tid], sf[3][tid]));
        }
        if (tid < 11) {
            atomicAdd(&gsum[rep * 11 + tid], r);
        } else if (tid < 19) {
            atomicAdd(&bsum[b * 8 + (tid - 11)], r);
        } else {
            const int g = tid - 19;            // 0..7: (mn,mx)x{2x,2y,3x,3y}
            const unsigned m = mapf(r);
            if ((g & 1) == 0) atomicMin(&bmn[b * 4 + (g >> 1)], m);
            else              atomicMax(&bmx[b * 4 + (g >> 1)], m);
        }
    } else if (tid >= 32 && tid < 41) {
        const int v = tid - 32;
        const unsigned r = si[0][v] + si[1][v] + si[2][v] + si[3][v];
        if (v < 5) {
            atomicAdd(&gcnt[rep * 5 + v], r);
            if (v >= 1) atomicAdd(&bcnt[b * 8 + (v - 1)], r);  // gtc = label counts 1..4
        } else {
            atomicAdd(&bcnt[b * 8 + 4 + (v - 5)], r);          // prc
        }
    }
}

// Tiny finalize: 1 block x 64 threads, reads ~3.5 KB total.
__global__ __launch_bounds__(64) void bsl_final(
    const float* __restrict__ gsum, const unsigned* __restrict__ gcnt,
    const float* __restrict__ bsum, const unsigned* __restrict__ bcnt,
    const unsigned* __restrict__ bmn, const unsigned* __restrict__ bmx,
    float* __restrict__ out)
{
    const int lane = threadIdx.x;
    __shared__ float smg[16];   // 0..10 S/T/lse, 11..15 dist

    if (lane < 16) {
        float s = 0.f;
        if (lane < 11) {
#pragma unroll
            for (int r = 0; r < NREP; ++r) s += gsum[r * 11 + lane];
        } else {
            unsigned u = 0;
#pragma unroll
            for (int r = 0; r < NREP; ++r) u += gcnt[r * 5 + (lane - 11)];
            s = (float)u;   // exact: <= 2^23
        }
        smg[lane] = s;
    }

    const float BASE_W[5] = {0.8f, 2.0f, 1.5f, 1.5f, 3.5f};
    const int pc[12]  = {1, 1, 1, 2, 2, 2, 3, 3, 3, 4, 4, 4};
    const int prf[12] = {2, 3, 4, 1, 3, 4, 1, 2, 4, 1, 2, 3};
    const float ps[12] = {-1.f, -1.f, -1.f, 1.f, -1.f, -1.f, 1.f, 1.f, -1.f, 1.f, 1.f, 1.f};

    // lane b (< BATCH) computes batch b's clipped weights; others contribute 0
    float w[5] = {0, 0, 0, 0, 0};
    if (lane < BATCH) {
        for (int c = 0; c < 5; ++c) w[c] = BASE_W[c];
        float gtm[4], prm[4];
        bool gv[4], pv[4];
#pragma unroll
        for (int k = 0; k < 4; ++k) {
            const unsigned c1 = bcnt[lane * 8 + k];
            gv[k] = (c1 > 0u);
            gtm[k] = bsum[lane * 8 + k] / fmaxf((float)c1, 1.f);
            const unsigned c2 = bcnt[lane * 8 + 4 + k];
            pv[k] = (c2 > 0u);
            prm[k] = bsum[lane * 8 + 4 + k] / fmaxf((float)c2, 1.f);
        }
#pragma unroll
        for (int p = 0; p < 12; ++p) {
            const int cid = pc[p], ref = prf[p];
            float add = 0.f;
            if (pv[cid - 1] && gv[ref - 1]) {
                const float diff = ps[p] * (prm[cid - 1] - gtm[ref - 1]);
                add = 50.f / (1.f + expf(10.f * diff));  // ALPHA*sigmoid(-10*diff)
            }
            w[cid] += add;
            w[ref] += 0.3f * add;
        }
        const float mn2x = unmapf(bmn[lane * 4 + 0]), mx2x = unmapf(bmx[lane * 4 + 0]);
        const float mn2y = unmapf(bmn[lane * 4 + 1]), mx2y = unmapf(bmx[lane * 4 + 1]);
        const float mn3x = unmapf(bmn[lane * 4 + 2]), mx3x = unmapf(bmx[lane * 4 + 2]);
        const float mn3y = unmapf(bmn[lane * 4 + 3]), mx3y = unmapf(bmx[lane * 4 + 3]);
        {   // cid=2 vs rb=bounds[3]
            const float dx = mx3x - mn3x + 1e-7f, dy = mx3y - mn3y + 1e-7f;
            const float xc0 = (mn2x - mn3x) / dx, xc1 = (mx2x - mn3x) / dx;
            const float yc0 = (mn2y - mn3y) / dy, yc1 = (mx2y - mn3y) / dy;
            const float v0 = (xc0 < 0.1f || xc0 > 0.9f || yc0 < 0.1f || yc0 > 0.9f) ? 1.f : 0.f;
            const float v1 = (xc1 < 0.1f || xc1 > 0.9f || yc1 < 0.1f || yc1 > 0.9f) ? 1.f : 0.f;
            w[2] += 50.f * 0.5f * (v0 + v1);
        }
        {   // cid=3 vs rb=bounds[2]
            const float dx = mx2x - mn2x + 1e-7f, dy = mx2y - mn2y + 1e-7f;
            const float xc0 = (mn3x - mn2x) / dx, xc1 = (mx3x - mn2x) / dx;
            const float yc0 = (mn3y - mn2y) / dy, yc1 = (mx3y - mn2y) / dy;
            const float v0 = (xc0 < 0.1f || xc0 > 0.9f || yc0 < 0.1f || yc0 > 0.9f) ? 1.f : 0.f;
            const float v1 = (xc1 < 0.1f || xc1 > 0.9f || yc1 < 0.1f || yc1 > 0.9f) ? 1.f : 0.f;
            w[3] += 50.f * 0.5f * (v0 + v1);
        }
#pragma unroll
        for (int c = 0; c < 5; ++c)
            w[c] = fminf(fmaxf(w[c], 0.1f), 10.f);
    }
    float wsumc[5];
#pragma unroll
    for (int c = 0; c < 5; ++c) wsumc[c] = wred_sum(w[c]);

    __syncthreads();
    if (lane == 0) {
        float dist[5], cw[5], s = 0.f;
#pragma unroll
        for (int c = 0; c < 5; ++c) {
            dist[c] = smg[11 + c];
            cw[c] = 1.f / (sqrtf(dist[c]) + 1e-7f);
            s += cw[c];
        }
        float wf[5], wsum = 0.f, W = 0.f, nllnum = 0.f, Ssum = 0.f;
#pragma unroll
        for (int c = 0; c < 5; ++c) {
            cw[c] = cw[c] / s * 5.f;
            wf[c] = (wsumc[c] / 32.f) * cw[c];
            wsum += wf[c] * dist[c];
            W += wf[c];
            nllnum += wf[c] * smg[5 + c];
            Ssum += wf[c] * smg[c];
        }
        const float nll = nllnum / wsum;
        const float smooth = (W * smg[10] - Ssum) / wsum;
        out[0] = 0.8f * nll + 0.04f * smooth;
    }
}

extern "C" void kernel_launch(void* const* d_in, const int* in_sizes, int n_in,
                              void* d_out, int out_size, void* d_ws, size_t ws_size,
                              hipStream_t stream) {
    const float* outputs = (const float*)d_in[0];
    const int*   labels  = (const int*)d_in[1];
    const float* points  = (const float*)d_in[2];
    float* out = (float*)d_out;

    char* base = (char*)d_ws;
    float*    gsum = (float*)(base + 0);      // 8*11 f  (352 B)
    unsigned* gcnt = (unsigned*)(base + 352); // 8*5  u  (160 B)
    float*    bsum = (float*)(base + 512);    // 32*8 f  (1024 B)
    unsigned* bcnt = (unsigned*)(base + 1536);// 32*8 u  (1024 B)
    unsigned* bmx  = (unsigned*)(base + 2560);// 32*4 u  (512 B)  zero-init
    unsigned* bmn  = (unsigned*)(base + 3072);// 32*4 u  (512 B)  0xFF-init

    const int iters = NPTS / (BPB * 1024);    // 4

    hipMemsetAsync(base, 0, 3072, stream);        // sums/counts/maxes -> 0
    hipMemsetAsync(base + 3072, 0xFF, 512, stream);  // mapped mins -> UINT_MAX
    bsl_main<<<NBLK, 256, 0, stream>>>(outputs, labels, points,
                                       gsum, gcnt, bsum, bcnt, bmn, bmx, iters);
    bsl_final<<<1, 64, 0, stream>>>(gsum, gcnt, bsum, bcnt, bmn, bmx, out);
}